// Round 18
// baseline (414.758 us; speedup 1.0000x reference)
//
#include <hip/hip_runtime.h>
#include <hip/hip_bf16.h>

#define S_LEN 2048
#define HID 2048
#define NB 2
#define NH 16
#define NKV 8
#define DH 128
#define RQ 6
#define KG 2048
#define SCALING 0.08838834764831845f

typedef __attribute__((ext_vector_type(8))) short s16x8;
typedef __attribute__((ext_vector_type(4))) float f32x4;

__device__ __forceinline__ float bf2f(ushort u) {
    union { unsigned int i; float f; } v; v.i = ((unsigned int)u) << 16; return v.f;
}
__device__ __forceinline__ ushort f2bf(float f) {
    __hip_bfloat16 h = __float2bfloat16(f);
    return *reinterpret_cast<ushort*>(&h);
}
__device__ __forceinline__ void g2lds16(const void* g, void* l) {
    __builtin_amdgcn_global_load_lds((const __attribute__((address_space(1))) void*)g,
                                     (__attribute__((address_space(3))) void*)l, 16, 0, 0);
}

// ---------------- fused prep: cvt(hs->Xb) + all 7 weight transposes, one launch ----------------
__global__ void k_prep(const float* __restrict__ hs, const float* __restrict__ WAq,
                       const float* __restrict__ WAk, const float* __restrict__ WAv,
                       const float* __restrict__ WBk, const float* __restrict__ WBv,
                       const float* __restrict__ WBq, const float* __restrict__ Wo,
                       ushort* __restrict__ Xb, ushort* __restrict__ WtS,
                       ushort* __restrict__ WtBq, ushort* __restrict__ WtWo) {
    __shared__ ushort tile[64][68];
    int idx = blockIdx.x;
    int t = threadIdx.x;
    if (idx < 2048) {
#pragma unroll
        for (int j = 0; j < 4; ++j) {
            int i = idx * 1024 + t + j * 256;
            float4 v = ((const float4*)hs)[i];
            ushort4 o;
            o.x = f2bf(v.x); o.y = f2bf(v.y); o.z = f2bf(v.z); o.w = f2bf(v.w);
            ((ushort4*)Xb)[i] = o;
        }
        return;
    }
    idx -= 2048;
    const float* in; ushort* out; int Nin, rowOff;
    if (idx < 64)        { in = WAq; out = WtS;  Nin = 96;    rowOff = 0; }
    else if (idx < 96)   { idx -= 64;   in = WAk; out = WtS;  Nin = 16;    rowOff = 96; }
    else if (idx < 128)  { idx -= 96;   in = WAv; out = WtS;  Nin = 16;    rowOff = 112; }
    else if (idx < 256)  { idx -= 128;  in = WBk; out = WtS;  Nin = 256;   rowOff = 128; }
    else if (idx < 384)  { idx -= 256;  in = WBv; out = WtS;  Nin = 256;   rowOff = 384; }
    else if (idx < 6528) { idx -= 384;  in = WBq; out = WtBq; Nin = 12288; rowOff = 0; }
    else                 { idx -= 6528; in = Wo;  out = WtWo; Nin = 2048;  rowOff = 0; }
    int k0 = (idx & 31) * 64, n0 = (idx >> 5) * 64;
#pragma unroll
    for (int i = 0; i < 4; ++i) {
        int f = t + i * 256;
        int r = f >> 4;
        int c = (f & 15) * 4;
        int nn = n0 + c;
        float4 v = make_float4(0.f, 0.f, 0.f, 0.f);
        if (nn < Nin) v = *(const float4*)&in[(size_t)(k0 + r) * Nin + nn];
        ushort4 u;
        u.x = f2bf(v.x); u.y = f2bf(v.y); u.z = f2bf(v.z); u.w = f2bf(v.w);
        *(ushort4*)&tile[r][c] = u;
    }
    __syncthreads();
#pragma unroll
    for (int i = 0; i < 4; ++i) {
        int f = t + i * 256;
        int nr = f >> 4;
        int kc = (f & 15) * 4;
        int nn = n0 + nr;
        if (nn < Nin) {
            ushort4 u;
            u.x = tile[kc][nr]; u.y = tile[kc + 1][nr];
            u.z = tile[kc + 2][nr]; u.w = tile[kc + 3][nr];
            *(ushort4*)&out[(size_t)(rowOff + nn) * KG + k0 + kc] = u;
        }
    }
}

// ---------------- generic bf16 GEMM: A[M][2048] @ Bt[N][2048]^T -> C[M][ldc], 128x128 tile ----------------
__device__ __forceinline__ void stc(float* p, float v) { *p = v; }
__device__ __forceinline__ void stc(ushort* p, float v) { *p = f2bf(v); }

template<typename OutT>
__global__ __launch_bounds__(256, 2) void k_gemm(const ushort* __restrict__ A,
                                                 const ushort* __restrict__ Bt,
                                                 OutT* __restrict__ C, int ldc) {
    __shared__ ushort lA[128 * 64];
    __shared__ ushort lB[128 * 64];
    const int tid = threadIdx.x;
    const int l = tid & 63, w = tid >> 6;
    const int gx = gridDim.x;
    int flat = blockIdx.y * gx + blockIdx.x;
    const int nwg = gx * gridDim.y;
    if ((nwg & 7) == 0) {
        int qq = nwg >> 3;
        flat = (flat & 7) * qq + (flat >> 3);
    }
    const int m0 = (flat % gx) * 128, n0 = (flat / gx) * 128;
    const int wm = w >> 1, wn = w & 1;
    f32x4 acc[4][4] = {};
    const int swz = 16 * ((tid & 7) ^ ((tid >> 3) & 7));
    const int rowbase = tid >> 3;

    for (int k0 = 0; k0 < KG; k0 += 64) {
#pragma unroll
        for (int i = 0; i < 4; ++i) {
            int row = rowbase + i * 32;
            const char* srcA = (const char*)A + (((size_t)(m0 + row) * KG + k0) * 2) + swz;
            g2lds16(srcA, (char*)lA + tid * 16 + i * 4096);
            const char* srcB = (const char*)Bt + (((size_t)(n0 + row) * KG + k0) * 2) + swz;
            g2lds16(srcB, (char*)lB + tid * 16 + i * 4096);
        }
        __syncthreads();
#pragma unroll
        for (int kk = 0; kk < 2; ++kk) {
            s16x8 af[4], bfr[4];
            const int kb = kk * 64 + (l >> 4) * 16;
#pragma unroll
            for (int mf = 0; mf < 4; ++mf) {
                int row = wm * 64 + mf * 16 + (l & 15);
                af[mf] = *(const s16x8*)((const char*)lA + row * 128 + (kb ^ ((row & 7) << 4)));
            }
#pragma unroll
            for (int nf = 0; nf < 4; ++nf) {
                int row = wn * 64 + nf * 16 + (l & 15);
                bfr[nf] = *(const s16x8*)((const char*)lB + row * 128 + (kb ^ ((row & 7) << 4)));
            }
#pragma unroll
            for (int mf = 0; mf < 4; ++mf)
#pragma unroll
                for (int nf = 0; nf < 4; ++nf)
                    acc[mf][nf] = __builtin_amdgcn_mfma_f32_16x16x32_bf16(af[mf], bfr[nf], acc[mf][nf], 0, 0, 0);
        }
        __syncthreads();
    }
#pragma unroll
    for (int mf = 0; mf < 4; ++mf)
#pragma unroll
        for (int r = 0; r < 4; ++r) {
            int row = m0 + wm * 64 + mf * 16 + (l >> 4) * 4 + r;
#pragma unroll
            for (int nf = 0; nf < 4; ++nf) {
                int col = n0 + wn * 64 + nf * 16 + (l & 15);
                stc(C + (size_t)row * ldc + col, acc[mf][nf][r]);
            }
        }
}

// ---------------- mega launch: gemm8(Bq, blocks 0..767) + Small GEMM (blocks 768..927) ----------------
__global__ __launch_bounds__(512, 2) void k_mega(const ushort* __restrict__ Xb,
                                                 const ushort* __restrict__ WtBq,
                                                 ushort* __restrict__ BqC,
                                                 const ushort* __restrict__ WtS,
                                                 float* __restrict__ Small) {
    __shared__ char sB[131072];
    const int tid = threadIdx.x;
    const int l = tid & 63, wid = tid >> 6;

    if (blockIdx.x < 768) {
        const ushort* A = Xb;
        const ushort* Bt = WtBq;
        ushort* C = BqC;
        const int ldc = 12288;
        const int wr = wid >> 2, wc = wid & 3;

        int flat = blockIdx.x;
        {
            int qq = 768 >> 3;
            flat = (flat & 7) * qq + (flat >> 3);
        }
        const int m0 = (flat & 15) * 256;
        const int n0 = (flat >> 4) * 256;

        const int rb = tid >> 3;
        const int swz = 16 * ((tid & 7) ^ (rb & 7));
        const char* pAh[2][2];
        const char* pBh[2][2];
#pragma unroll
        for (int h = 0; h < 2; ++h)
#pragma unroll
            for (int j = 0; j < 2; ++j) {
                pAh[h][j] = (const char*)A + (size_t)(m0 + j * 128 + h * 64 + rb) * (KG * 2) + swz;
                pBh[h][j] = (const char*)Bt + (size_t)(n0 + (j * 2 + (tid >> 8)) * 64 + h * 32 + (rb & 31)) * (KG * 2) + swz;
            }

        f32x4 acc[8][4] = {};
        s16x8 af[4][2], bf[4][2];

        const int arow = (l & 15) * 128;
        const int kxor0 = (0 * 64 + (l >> 4) * 16) ^ ((l & 7) << 4);
        const int kxor1 = (1 * 64 + (l >> 4) * 16) ^ ((l & 7) << 4);

#define STG_A(T, D, H)                                                                     \
    do {                                                                                   \
        g2lds16(pAh[H][0] + (size_t)(T) * 128, sB + (D) * 65536 + (H) * 16384 + tid * 16); \
        g2lds16(pAh[H][1] + (size_t)(T) * 128, sB + (D) * 65536 + (H) * 16384 + 8192 + tid * 16); \
    } while (0)
#define STG_B(T, D, H)                                                                     \
    do {                                                                                   \
        g2lds16(pBh[H][0] + (size_t)(T) * 128, sB + (D) * 65536 + 32768 + (H) * 16384 + tid * 16); \
        g2lds16(pBh[H][1] + (size_t)(T) * 128, sB + (D) * 65536 + 32768 + (H) * 16384 + 8192 + tid * 16); \
    } while (0)
#define RD_A(D, MH)                                                                        \
    do {                                                                                   \
        const char* ab = sB + (D) * 65536 + (MH) * 16384 + wr * 8192;                      \
        _Pragma("unroll") for (int mi = 0; mi < 4; ++mi) {                                 \
            af[mi][0] = *(const s16x8*)(ab + mi * 2048 + arow + kxor0);                    \
            af[mi][1] = *(const s16x8*)(ab + mi * 2048 + arow + kxor1);                    \
        }                                                                                  \
    } while (0)
#define RD_B(D, BH)                                                                        \
    do {                                                                                   \
        const char* bb = sB + (D) * 65536 + 32768 + (BH) * 16384 + wc * 4096;              \
        _Pragma("unroll") for (int ni = 0; ni < 2; ++ni) {                                 \
            bf[(BH) * 2 + ni][0] = *(const s16x8*)(bb + ni * 2048 + arow + kxor0);         \
            bf[(BH) * 2 + ni][1] = *(const s16x8*)(bb + ni * 2048 + arow + kxor1);         \
        }                                                                                  \
    } while (0)
#define QMFMA(MQ, NQ)                                                                      \
    do {                                                                                   \
        __builtin_amdgcn_s_setprio(1);                                                     \
        _Pragma("unroll") for (int mi = 0; mi < 4; ++mi)                                   \
        _Pragma("unroll") for (int ni = 0; ni < 2; ++ni)                                   \
        _Pragma("unroll") for (int k2 = 0; k2 < 2; ++k2)                                   \
            acc[(MQ) * 4 + mi][(NQ) * 2 + ni] = __builtin_amdgcn_mfma_f32_16x16x32_bf16(   \
                af[mi][k2], bf[(NQ) * 2 + ni][k2], acc[(MQ) * 4 + mi][(NQ) * 2 + ni], 0, 0, 0); \
        __builtin_amdgcn_s_setprio(0);                                                     \
    } while (0)
#define BAR()                                   \
    do {                                        \
        asm volatile("" ::: "memory");          \
        __builtin_amdgcn_s_barrier();           \
        asm volatile("" ::: "memory");          \
    } while (0)
#define VM6() asm volatile("s_waitcnt vmcnt(6)" ::: "memory")
#define VM0() asm volatile("s_waitcnt vmcnt(0)" ::: "memory")

        STG_A(0, 0, 0); STG_A(0, 0, 1); STG_B(0, 0, 0); STG_B(0, 0, 1);
        STG_B(1, 1, 0); STG_B(1, 1, 1); STG_A(1, 1, 0);
        VM6();
        BAR();

        for (int i = 0; i < 16; ++i) {
            const bool last = (i == 15);
            const int t1 = 2 * i + 1, t2 = 2 * i + 2, t3 = 2 * i + 3;
            RD_A(0, 0); RD_B(0, 0);
            STG_A(t1, 1, 1);
            BAR(); QMFMA(0, 0); BAR();
            RD_B(0, 1);
            if (!last) STG_A(t2, 0, 0);
            BAR(); QMFMA(0, 1); BAR();
            RD_A(0, 1);
            if (!last) STG_B(t2, 0, 0);
            BAR(); QMFMA(1, 1); BAR();
            if (!last) { STG_B(t2, 0, 1); VM6(); } else { VM0(); }
            BAR(); QMFMA(1, 0); BAR();
            RD_A(1, 0); RD_B(1, 0);
            if (!last) STG_A(t2, 0, 1);
            BAR(); QMFMA(0, 0); BAR();
            RD_B(1, 1);
            if (!last) STG_B(t3, 1, 0);
            BAR(); QMFMA(0, 1); BAR();
            RD_A(1, 1);
            if (!last) STG_B(t3, 1, 1);
            BAR(); QMFMA(1, 1); BAR();
            if (!last) { STG_A(t3, 1, 0); VM6(); }
            BAR(); QMFMA(1, 0); BAR();
        }

#undef STG_A
#undef STG_B
#undef RD_A
#undef RD_B
#undef QMFMA
#undef BAR
#undef VM6
#undef VM0

#pragma unroll
        for (int mf = 0; mf < 8; ++mf)
#pragma unroll
            for (int r = 0; r < 4; ++r) {
                int row = m0 + wr * 128 + mf * 16 + (l >> 4) * 4 + r;
#pragma unroll
                for (int nf = 0; nf < 4; ++nf) {
                    int col = n0 + wc * 64 + nf * 16 + (l & 15);
                    C[(size_t)row * ldc + col] = f2bf(acc[mf][nf][r]);
                }
            }
    } else {
        // ---- Small GEMM: Xb @ WtS^T -> Small[4096][640] f32, 128x128 tile ----
        ushort* lA = (ushort*)sB;
        ushort* lB = (ushort*)(sB + 16384);
        int flat = blockIdx.x - 768;
        {
            int qq = 160 >> 3;
            flat = (flat & 7) * qq + (flat >> 3);
        }
        const int m0 = (flat % 32) * 128, n0 = (flat / 32) * 128;
        const int w = wid;
        const int wm = (w & 3) >> 1, wn = w & 1;
        f32x4 acc[4][4] = {};
        const int swz = 16 * ((tid & 7) ^ ((tid >> 3) & 7));
        const int rowbase = tid >> 3;

        for (int k0 = 0; k0 < KG; k0 += 64) {
#pragma unroll
            for (int i = 0; i < 2; ++i) {
                int row = rowbase + i * 64;
                const char* srcA = (const char*)Xb + (((size_t)(m0 + row) * KG + k0) * 2) + swz;
                g2lds16(srcA, (char*)lA + tid * 16 + i * 8192);
                const char* srcB = (const char*)WtS + (((size_t)(n0 + row) * KG + k0) * 2) + swz;
                g2lds16(srcB, (char*)lB + tid * 16 + i * 8192);
            }
            __syncthreads();
            if (w < 4) {
#pragma unroll
                for (int kk = 0; kk < 2; ++kk) {
                    s16x8 af[4], bfr[4];
                    const int kb = kk * 64 + (l >> 4) * 16;
#pragma unroll
                    for (int mf = 0; mf < 4; ++mf) {
                        int row = wm * 64 + mf * 16 + (l & 15);
                        af[mf] = *(const s16x8*)((const char*)lA + row * 128 + (kb ^ ((row & 7) << 4)));
                    }
#pragma unroll
                    for (int nf = 0; nf < 4; ++nf) {
                        int row = wn * 64 + nf * 16 + (l & 15);
                        bfr[nf] = *(const s16x8*)((const char*)lB + row * 128 + (kb ^ ((row & 7) << 4)));
                    }
#pragma unroll
                    for (int mf = 0; mf < 4; ++mf)
#pragma unroll
                        for (int nf = 0; nf < 4; ++nf)
                            acc[mf][nf] = __builtin_amdgcn_mfma_f32_16x16x32_bf16(af[mf], bfr[nf], acc[mf][nf], 0, 0, 0);
                }
            }
            __syncthreads();
        }
        if (w < 4) {
#pragma unroll
            for (int mf = 0; mf < 4; ++mf)
#pragma unroll
                for (int r = 0; r < 4; ++r) {
                    int row = m0 + wm * 64 + mf * 16 + (l >> 4) * 4 + r;
#pragma unroll
                    for (int nf = 0; nf < 4; ++nf) {
                        int col = n0 + wn * 64 + nf * 16 + (l & 15);
                        Small[(size_t)row * 640 + col] = acc[mf][nf][r];
                    }
                }
        }
    }
}

// ---------------- 256x256 8-phase counted-vmcnt GEMM (small-ws fallback only) ----------------
__global__ __launch_bounds__(512, 2) void k_gemm8(const ushort* __restrict__ A,
                                                  const ushort* __restrict__ Bt,
                                                  ushort* __restrict__ C, int ldc) {
    __shared__ char sB[131072];
    const int tid = threadIdx.x;
    const int l = tid & 63, wid = tid >> 6;
    const int wr = wid >> 2, wc = wid & 3;

    int flat = blockIdx.x;
    const int nwg = gridDim.x;
    if ((nwg & 7) == 0) {
        int qq = nwg >> 3;
        flat = (flat & 7) * qq + (flat >> 3);
    }
    const int m0 = (flat & 15) * 256;
    const int n0 = (flat >> 4) * 256;

    const int rb = tid >> 3;
    const int swz = 16 * ((tid & 7) ^ (rb & 7));
    const char* pAh[2][2];
    const char* pBh[2][2];
#pragma unroll
    for (int h = 0; h < 2; ++h)
#pragma unroll
        for (int j = 0; j < 2; ++j) {
            pAh[h][j] = (const char*)A + (size_t)(m0 + j * 128 + h * 64 + rb) * (KG * 2) + swz;
            pBh[h][j] = (const char*)Bt + (size_t)(n0 + (j * 2 + (tid >> 8)) * 64 + h * 32 + (rb & 31)) * (KG * 2) + swz;
        }

    f32x4 acc[8][4] = {};
    s16x8 af[4][2], bf[4][2];

    const int arow = (l & 15) * 128;
    const int kxor0 = (0 * 64 + (l >> 4) * 16) ^ ((l & 7) << 4);
    const int kxor1 = (1 * 64 + (l >> 4) * 16) ^ ((l & 7) << 4);

#define STG_A(T, D, H)                                                                     \
    do {                                                                                   \
        g2lds16(pAh[H][0] + (size_t)(T) * 128, sB + (D) * 65536 + (H) * 16384 + tid * 16); \
        g2lds16(pAh[H][1] + (size_t)(T) * 128, sB + (D) * 65536 + (H) * 16384 + 8192 + tid * 16); \
    } while (0)
#define STG_B(T, D, H)                                                                     \
    do {                                                                                   \
        g2lds16(pBh[H][0] + (size_t)(T) * 128, sB + (D) * 65536 + 32768 + (H) * 16384 + tid * 16); \
        g2lds16(pBh[H][1] + (size_t)(T) * 128, sB + (D) * 65536 + 32768 + (H) * 16384 + 8192 + tid * 16); \
    } while (0)
#define RD_A(D, MH)                                                                        \
    do {                                                                                   \
        const char* ab = sB + (D) * 65536 + (MH) * 16384 + wr * 8192;                      \
        _Pragma("unroll") for (int mi = 0; mi < 4; ++mi) {                                 \
            af[mi][0] = *(const s16x8*)(ab + mi * 2048 + arow + kxor0);                    \
            af[mi][1] = *(const s16x8*)(ab + mi * 2048 + arow + kxor1);                    \
        }                                                                                  \
    } while (0)
#define RD_B(D, BH)                                                                        \
    do {                                                                                   \
        const char* bb = sB + (D) * 65536 + 32768 + (BH) * 16384 + wc * 4096;              \
        _Pragma("unroll") for (int ni = 0; ni < 2; ++ni) {                                 \
            bf[(BH) * 2 + ni][0] = *(const s16x8*)(bb + ni * 2048 + arow + kxor0);         \
            bf[(BH) * 2 + ni][1] = *(const s16x8*)(bb + ni * 2048 + arow + kxor1);         \
        }                                                                                  \
    } while (0)
#define QMFMA(MQ, NQ)                                                                      \
    do {                                                                                   \
        __builtin_amdgcn_s_setprio(1);                                                     \
        _Pragma("unroll") for (int mi = 0; mi < 4; ++mi)                                   \
        _Pragma("unroll") for (int ni = 0; ni < 2; ++ni)                                   \
        _Pragma("unroll") for (int k2 = 0; k2 < 2; ++k2)                                   \
            acc[(MQ) * 4 + mi][(NQ) * 2 + ni] = __builtin_amdgcn_mfma_f32_16x16x32_bf16(   \
                af[mi][k2], bf[(NQ) * 2 + ni][k2], acc[(MQ) * 4 + mi][(NQ) * 2 + ni], 0, 0, 0); \
        __builtin_amdgcn_s_setprio(0);                                                     \
    } while (0)
#define BAR()                                   \
    do {                                        \
        asm volatile("" ::: "memory");          \
        __builtin_amdgcn_s_barrier();           \
        asm volatile("" ::: "memory");          \
    } while (0)
#define VM6() asm volatile("s_waitcnt vmcnt(6)" ::: "memory")
#define VM0() asm volatile("s_waitcnt vmcnt(0)" ::: "memory")

    STG_A(0, 0, 0); STG_A(0, 0, 1); STG_B(0, 0, 0); STG_B(0, 0, 1);
    STG_B(1, 1, 0); STG_B(1, 1, 1); STG_A(1, 1, 0);
    VM6();
    BAR();

    for (int i = 0; i < 16; ++i) {
        const bool last = (i == 15);
        const int t1 = 2 * i + 1, t2 = 2 * i + 2, t3 = 2 * i + 3;
        RD_A(0, 0); RD_B(0, 0);
        STG_A(t1, 1, 1);
        BAR(); QMFMA(0, 0); BAR();
        RD_B(0, 1);
        if (!last) STG_A(t2, 0, 0);
        BAR(); QMFMA(0, 1); BAR();
        RD_A(0, 1);
        if (!last) STG_B(t2, 0, 0);
        BAR(); QMFMA(1, 1); BAR();
        if (!last) { STG_B(t2, 0, 1); VM6(); } else { VM0(); }
        BAR(); QMFMA(1, 0); BAR();
        RD_A(1, 0); RD_B(1, 0);
        if (!last) STG_A(t2, 0, 1);
        BAR(); QMFMA(0, 0); BAR();
        RD_B(1, 1);
        if (!last) STG_B(t3, 1, 0);
        BAR(); QMFMA(0, 1); BAR();
        RD_A(1, 1);
        if (!last) STG_B(t3, 1, 1);
        BAR(); QMFMA(1, 1); BAR();
        if (!last) { STG_A(t3, 1, 0); VM6(); }
        BAR(); QMFMA(1, 0); BAR();
    }

#undef STG_A
#undef STG_B
#undef RD_A
#undef RD_B
#undef QMFMA

#pragma unroll
    for (int mf = 0; mf < 8; ++mf)
#pragma unroll
        for (int r = 0; r < 4; ++r) {
            int row = m0 + wr * 128 + mf * 16 + (l >> 4) * 4 + r;
#pragma unroll
            for (int nf = 0; nf < 4; ++nf) {
                int col = n0 + wc * 64 + nf * 16 + (l & 15);
                C[(size_t)row * ldc + col] = f2bf(acc[mf][nf][r]);
            }
        }
#undef BAR
#undef VM6
#undef VM0
}

// ---------------- 128x256 8-phase counted-vmcnt GEMM (BK=64, dbuf), f32 out ----------------
__global__ __launch_bounds__(512, 2) void k_gemm8h(const ushort* __restrict__ A,
                                                   const ushort* __restrict__ Bt,
                                                   float* __restrict__ C, int ldc) {
    __shared__ char sB[98304];
    const int tid = threadIdx.x;
    const int l = tid & 63, wid = tid >> 6;
    const int wr = wid >> 2, wc = wid & 3;

    int flat = blockIdx.x;
    const int nwg = gridDim.x;
    if ((nwg & 7) == 0) {
        int qq = nwg >> 3;
        flat = (flat & 7) * qq + (flat >> 3);
    }
    const int m0 = (flat & 31) * 128;
    const int n0 = (flat >> 5) * 256;

    const int rb = tid >> 3;
    const int swz = 16 * ((tid & 7) ^ (rb & 7));
    const char* pA_[2];
    const char* pB_[2][2];
#pragma unroll
    for (int h = 0; h < 2; ++h) {
        pA_[h] = (const char*)A + (size_t)(m0 + (tid >> 8) * 64 + h * 32 + (rb & 31)) * (KG * 2) + swz;
#pragma unroll
        for (int j = 0; j < 2; ++j)
            pB_[h][j] = (const char*)Bt + (size_t)(n0 + (j * 2 + (tid >> 8)) * 64 + h * 32 + (rb & 31)) * (KG * 2) + swz;
    }

    f32x4 acc[4][4] = {};
    s16x8 af[2][2], bf[4][2];

    const int arow = (l & 15) * 128;
    const int kxor0 = ((l >> 4) * 16) ^ ((l & 7) << 4);
    const int kxor1 = (64 + (l >> 4) * 16) ^ ((l & 7) << 4);

#define STG_AH(T, D, H)                                                                    \
    g2lds16(pA_[H] + (size_t)(T) * 128, sB + (D) * 49152 + (H) * 8192 + tid * 16)
#define STG_BH(T, D, H)                                                                    \
    do {                                                                                   \
        g2lds16(pB_[H][0] + (size_t)(T) * 128, sB + (D) * 49152 + 16384 + (H) * 16384 + tid * 16); \
        g2lds16(pB_[H][1] + (size_t)(T) * 128, sB + (D) * 49152 + 16384 + (H) * 16384 + 8192 + tid * 16); \
    } while (0)
#define RD_AH(D, MH)                                                                       \
    do {                                                                                   \
        const char* ab = sB + (D) * 49152 + (MH) * 8192 + wr * 4096;                       \
        _Pragma("unroll") for (int mi = 0; mi < 2; ++mi) {                                 \
            af[mi][0] = *(const s16x8*)(ab + mi * 2048 + arow + kxor0);                    \
            af[mi][1] = *(const s16x8*)(ab + mi * 2048 + arow + kxor1);                    \
        }                                                                                  \
    } while (0)
#define RD_BH(D, BH)                                                                       \
    do {                                                                                   \
        const char* bb = sB + (D) * 49152 + 16384 + (BH) * 16384 + wc * 4096;              \
        _Pragma("unroll") for (int ni = 0; ni < 2; ++ni) {                                 \
            bf[(BH) * 2 + ni][0] = *(const s16x8*)(bb + ni * 2048 + arow + kxor0);         \
            bf[(BH) * 2 + ni][1] = *(const s16x8*)(bb + ni * 2048 + arow + kxor1);         \
        }                                                                                  \
    } while (0)
#define QMFMAH(MQ, NQ)                                                                     \
    do {                                                                                   \
        __builtin_amdgcn_s_setprio(1);                                                     \
        _Pragma("unroll") for (int mi = 0; mi < 2; ++mi)                                   \
        _Pragma("unroll") for (int ni = 0; ni < 2; ++ni)                                   \
        _Pragma("unroll") for (int k2 = 0; k2 < 2; ++k2)                                   \
            acc[(MQ) * 2 + mi][(NQ) * 2 + ni] = __builtin_amdgcn_mfma_f32_16x16x32_bf16(   \
                af[mi][k2], bf[(NQ) * 2 + ni][k2], acc[(MQ) * 2 + mi][(NQ) * 2 + ni], 0, 0, 0); \
        __builtin_amdgcn_s_setprio(0);                                                     \
    } while (0)
#define BAR()                                   \
    do {                                        \
        asm volatile("" ::: "memory");          \
        __builtin_amdgcn_s_barrier();           \
        asm volatile("" ::: "memory");          \
    } while (0)
#define VM5() asm volatile("s_waitcnt vmcnt(5)" ::: "memory")
#define VM0() asm volatile("s_waitcnt vmcnt(0)" ::: "memory")

    STG_AH(0, 0, 0); STG_AH(0, 0, 1); STG_BH(0, 0, 0); STG_BH(0, 0, 1);
    STG_BH(1, 1, 0); STG_BH(1, 1, 1); STG_AH(1, 1, 0);
    VM5();
    BAR();

    for (int i = 0; i < 16; ++i) {
        const bool last = (i == 15);
        const int t1 = 2 * i + 1, t2 = 2 * i + 2, t3 = 2 * i + 3;
        RD_AH(0, 0); RD_BH(0, 0);
        STG_AH(t1, 1, 1);
        BAR(); QMFMAH(0, 0); BAR();
        RD_BH(0, 1);
        if (!last) STG_AH(t2, 0, 0);
        BAR(); QMFMAH(0, 1); BAR();
        RD_AH(0, 1);
        if (!last) STG_BH(t2, 0, 0);
        BAR(); QMFMAH(1, 1); BAR();
        if (!last) { STG_BH(t2, 0, 1); VM5(); } else { VM0(); }
        BAR(); QMFMAH(1, 0); BAR();
        RD_AH(1, 0); RD_BH(1, 0);
        if (!last) STG_AH(t2, 0, 1);
        BAR(); QMFMAH(0, 0); BAR();
        RD_BH(1, 1);
        if (!last) STG_BH(t3, 1, 0);
        BAR(); QMFMAH(0, 1); BAR();
        RD_AH(1, 1);
        if (!last) STG_BH(t3, 1, 1);
        BAR(); QMFMAH(1, 1); BAR();
        if (!last) { STG_AH(t3, 1, 0); VM5(); }
        BAR(); QMFMAH(1, 0); BAR();
    }

#undef STG_AH
#undef STG_BH
#undef RD_AH
#undef RD_BH
#undef QMFMAH
#undef BAR
#undef VM5
#undef VM0

#pragma unroll
    for (int a = 0; a < 4; ++a)
#pragma unroll
        for (int r = 0; r < 4; ++r) {
            int row = m0 + wr * 64 + a * 16 + (l >> 4) * 4 + r;
#pragma unroll
            for (int b2 = 0; b2 < 4; ++b2) {
                int col = n0 + wc * 64 + b2 * 16 + (l & 15);
                C[(size_t)row * ldc + col] = acc[a][b2][r];
            }
        }
}

// ---------------- contract ranks + rope + scale for q (small-ws fallback only) ----------------
__global__ void k_contract_q(const ushort* __restrict__ bq, const float* __restrict__ small,
                             const float* __restrict__ cosT, const float* __restrict__ sinT,
                             ushort* __restrict__ q, int pitch, int hbase) {
    int srow = blockIdx.x;
    int b = srow >> 11, sl = srow & 2047;
    int t = threadIdx.x;
    int l = t & 63;
    int hloc = blockIdx.y * 4 + (t >> 6);
    int h = hbase + hloc;
    const ushort* bqr = bq + (size_t)srow * pitch + hloc * 768;
    const float* af = small + (size_t)srow * 640 + h * RQ;
    float y0 = 0.f, y1 = 0.f;
#pragma unroll
    for (int r = 0; r < RQ; ++r) {
        float a = af[r];
        ushort2 v = *(const ushort2*)&bqr[r * 128 + 2 * l];
        y0 += a * bf2f(v.x);
        y1 += a * bf2f(v.y);
    }
    float z0 = __shfl_xor(y0, 32);
    float z1 = __shfl_xor(y1, 32);
    int d = (l & 31) * 2;
    float2 cs = *(const float2*)&cosT[sl * 64 + d];
    float2 sn = *(const float2*)&sinT[sl * 64 + d];
    size_t o = ((size_t)(b * NH + h) * S_LEN + sl) * DH;
    ushort2 outv;
    if (l < 32) {
        outv.x = f2bf((y0 * cs.x - z0 * sn.x) * SCALING);
        outv.y = f2bf((y1 * cs.y - z1 * sn.y) * SCALING);
        *(ushort2*)&q[o + d] = outv;
    } else {
        outv.x = f2bf((z0 * sn.x + y0 * cs.x) * SCALING);
        outv.y = f2bf((z1 * sn.y + y1 * cs.y) * SCALING);
        *(ushort2*)&q[o + 64 + d] = outv;
    }
}

// ---------------- contract ranks for k (rope) and v (write v^T) ----------------
__global__ void k_contract_kv(const float* __restrict__ small, const float* __restrict__ cosT,
                              const float* __restrict__ sinT, ushort* __restrict__ kk,
                              ushort* __restrict__ vT) {
    int srow = blockIdx.x;
    int b = srow >> 11, sl = srow & 2047;
    int t = threadIdx.x;                 // 512 threads
    int d2 = t & 63, g = t >> 6;         // g 0..7
    const float* row = small + (size_t)srow * 640;
    float k1 = 0.f, k2 = 0.f, v1 = 0.f, v2 = 0.f;
#pragma unroll
    for (int r = 0; r < 2; ++r) {
        float ak = row[96 + g * 2 + r];
        k1 += ak * row[128 + r * 128 + d2];
        k2 += ak * row[128 + r * 128 + 64 + d2];
        float av = row[112 + g * 2 + r];
        v1 += av * row[384 + r * 128 + d2];
        v2 += av * row[384 + r * 128 + 64 + d2];
    }
    float c = cosT[sl * 64 + d2], s = sinT[sl * 64 + d2];
    float kr1 = k1 * c - k2 * s, kr2 = k1 * s + k2 * c;
    size_t ko = ((size_t)(b * NKV + g) * S_LEN + sl) * DH + d2;
    kk[ko] = f2bf(kr1);
    kk[ko + 64] = f2bf(kr2);
    size_t vo = ((size_t)(b * NKV + g) * DH + d2) * S_LEN + sl;
    vT[vo] = f2bf(v1);
    vT[vo + (size_t)64 * S_LEN] = f2bf(v2);
}

// ---------------- softcap probability: exp(50*tanh(x/50) - 50) via Pade(5,4) tanh ----------------
__device__ __forceinline__ float softcap_p(float x) {
    float z = x * 0.02f;
    float z2 = z * z;
    float num = z * fmaf(z2, z2 + 105.f, 945.f);
    float den = fmaf(z2, fmaf(z2, 15.f, 420.f), 945.f);
    return __expf(fmaf(50.f, __fdividef(num, den), -50.f));
}

// ---------------- flash attention: R2 geometry + 4-way balanced qb schedule ----------------
// Dispatch model (R16 evidence): within an XCD, CU c receives j = c, c+32, c+64, c+96
// (round-robin across 32 CUs). Those 4 blocks share s = j&31 and differ in (hh = (j&63)>>5,
// bh = j>>6). qb(s,hh,bh) chosen so the 4 works sum to exactly 51 for every s:
//   (0,0): s        (1,0): 31-s        (0,1): (s+16)&31        (1,1): (15-s)&31
// s<=15: (s+1)+17+17+(16-s)=51; s>=16: 17+(32-s)+(s-15)+17=51. Each map bijective -> coverage.
template<int FUSEQ>
__global__ __launch_bounds__(256, 2) void k_attn(const ushort* __restrict__ qsrc,
                                                 const float* __restrict__ small,
                                                 const float* __restrict__ cosT,
                                                 const float* __restrict__ sinT,
                                                 const ushort* __restrict__ kk,
                                                 const ushort* __restrict__ vT,
                                                 ushort* __restrict__ O) {
    __shared__ char sK[16384];   // [64 tok][128 d] bf16, swizzled
    __shared__ char sV[16384];   // [128 d][64 tok] bf16, swizzled
    __shared__ char sP[8192];    // per-wave 2KB x 4
    const int f = blockIdx.x;        // 0..1023
    const int xcd = f & 7;
    const int j = f >> 3;            // 0..127
    const int bh = j >> 6;
    const int inner = j & 63;
    const int hh = inner >> 5;
    const int s = inner & 31;
    int qb;
    if (hh == 0 && bh == 0)      qb = s;
    else if (hh == 1 && bh == 0) qb = 31 - s;
    else if (hh == 0)            qb = (s + 16) & 31;
    else                         qb = (15 - s) & 31;
    const int bg = xcd * 2 + bh;
    const int b = bg >> 3, g = bg & 7;
    const int h = g * 2 + hh;
    const int tid = threadIdx.x, l = tid & 63, w = tid >> 6;   // w 0..3
    const int qs = qb * 64;
    const int q0 = qs + w * 16;

    s16x8 qf[4];
    if (FUSEQ) {
        const int row = q0 + (l & 15);
        const int srow = b * S_LEN + row;
        const float* af = small + (size_t)srow * 640 + h * RQ;
        const ushort* bqr = qsrc + (size_t)srow * 12288 + h * 768;
        const int k8 = (l >> 4) * 8;
#pragma unroll
        for (int grp = 0; grp < 2; ++grp) {
            const int dbase = grp * 32 + k8;
            float x1[8] = {}, x2[8] = {};
#pragma unroll
            for (int r = 0; r < RQ; ++r) {
                float a = af[r];
                s16x8 v1 = *(const s16x8*)&bqr[r * 128 + dbase];
                s16x8 v2 = *(const s16x8*)&bqr[r * 128 + 64 + dbase];
#pragma unroll
                for (int e = 0; e < 8; ++e) {
                    x1[e] = fmaf(a, bf2f((ushort)v1[e]), x1[e]);
                    x2[e] = fmaf(a, bf2f((ushort)v2[e]), x2[e]);
                }
            }
            const float* cp = &cosT[row * 64 + dbase];
            const float* sp = &sinT[row * 64 + dbase];
            s16x8 lo, hi;
#pragma unroll
            for (int e = 0; e < 8; ++e) {
                float c = cp[e], sv = sp[e];
                lo[e] = (short)f2bf((x1[e] * c - x2[e] * sv) * SCALING);
                hi[e] = (short)f2bf((x1[e] * sv + x2[e] * c) * SCALING);
            }
            qf[grp] = lo;
            qf[grp + 2] = hi;
        }
    } else {
        const ushort* qbase = qsrc + ((size_t)(b * NH + h) * S_LEN) * DH;
        const char* qrow = (const char*)(qbase + (size_t)(q0 + (l & 15)) * DH);
#pragma unroll
        for (int ds = 0; ds < 4; ++ds)
            qf[ds] = *(const s16x8*)(qrow + ds * 64 + (l >> 4) * 16);
    }

    f32x4 acc[8] = {};
    float lrow[4] = {0.f, 0.f, 0.f, 0.f};

    const size_t kgbase = ((size_t)(b * NKV + g) * S_LEN) * DH * 2;
    const size_t vgbase = ((size_t)(b * NKV + g) * DH) * S_LEN * 2;

    const int jt0 = (qs > 1023) ? ((qs - 1023) >> 6) : 0;
    const int ibase = q0 + (l >> 4) * 4;

    for (int jt = jt0; jt <= qb; ++jt) {
#pragma unroll
        for (int i = 0; i < 4; ++i) {
            int row = (tid >> 4) + i * 16;
            int colb = (tid & 15) * 16;
            const char* src = (const char*)kk + kgbase + ((size_t)(jt * 64 + row)) * 256 + (colb ^ ((row & 7) << 4));
            g2lds16(src, sK + tid * 16 + i * 4096);
        }
#pragma unroll
        for (int i = 0; i < 4; ++i) {
            int row = (tid >> 3) + i * 32;
            int colb = (tid & 7) * 16;
            const char* src = (const char*)vT + vgbase + (size_t)row * 4096 + (size_t)jt * 128 + (colb ^ ((row & 7) << 4));
            g2lds16(src, sV + tid * 16 + i * 4096);
        }
        __syncthreads();

        const bool diag = (jt == qb);
        const bool wclip = (jt == jt0) && (qs > 1023);

        f32x4 sc[4] = {};
#pragma unroll
        for (int ct = 0; ct < 4; ++ct) {
            if (diag && ct > w) continue;
            f32x4 z = {};
            int row = ct * 16 + (l & 15);
#pragma unroll
            for (int ds = 0; ds < 4; ++ds) {
                int kb = ds * 64 + (l >> 4) * 16;
                s16x8 kf = *(const s16x8*)(sK + row * 256 + (kb ^ ((row & 7) << 4)));
                z = __builtin_amdgcn_mfma_f32_16x16x32_bf16(qf[ds], kf, z, 0, 0, 0);
            }
            sc[ct] = z;
        }
        float p[4][4];
        if (!diag && !wclip) {
#pragma unroll
            for (int ct = 0; ct < 4; ++ct)
#pragma unroll
                for (int r = 0; r < 4; ++r) {
                    float pe = softcap_p(sc[ct][r]);
                    p[ct][r] = pe;
                    lrow[r] += pe;
                }
        } else if (diag) {
#pragma unroll
            for (int ct = 0; ct < 4; ++ct) {
                if (ct > w) {
#pragma unroll
                    for (int r = 0; r < 4; ++r) p[ct][r] = 0.f;
                    continue;
                }
                int j2 = jt * 64 + ct * 16 + (l & 15);
#pragma unroll
                for (int r = 0; r < 4; ++r) {
                    float pe = softcap_p(sc[ct][r]);
                    pe = (j2 <= ibase + r) ? pe : 0.f;
                    p[ct][r] = pe;
                    lrow[r] += pe;
                }
            }
        } else {
#pragma unroll
            for (int ct = 0; ct < 4; ++ct) {
                int j2 = jt * 64 + ct * 16 + (l & 15);
#pragma unroll
                for (int r = 0; r < 4; ++r) {
                    float pe = softcap_p(sc[ct][r]);
                    pe = (j2 > ibase + r - 1024) ? pe : 0.f;
                    p[ct][r] = pe;
                    lrow[r] += pe;
                }
            }
        }
#pragma unroll
        for (int ct = 0; ct < 4; ++ct) {
            int col = ct * 16 + (l & 15);
#pragma unroll
            for (int r = 0; r < 4; ++r) {
                int row = (l >> 4) * 4 + r;
                *(ushort*)(sP + w * 2048 + row * 128 + ((col * 2) ^ ((row & 7) << 4))) = f2bf(p[ct][r]);
            }
        }
#pragma unroll
        for (int s2 = 0; s2 < 2; ++s2) {
            int rowp = l & 15;
            int kb = s2 * 64 + (l >> 4) * 16;
            s16x8 pf = *(const s16x8*)(sP + w * 2048 + rowp * 128 + (kb ^ ((rowp & 7) << 4)));
#pragma unroll
            for (int dt = 0; dt < 8; ++dt) {
                int d = dt * 16 + (l & 15);
                s16x8 vf = *(const s16x8*)(sV + d * 128 + (kb ^ ((d & 7) << 4)));
                acc[dt] = __builtin_amdgcn_mfma_f32_16x16x32_bf16(pf, vf, acc[dt], 0, 0, 0);
            }
        }
        __syncthreads();
    }
#pragma unroll
    for (int r = 0; r < 4; ++r) {
        float rs = lrow[r];
        rs += __shfl_xor(rs, 1); rs += __shfl_xor(rs, 2);
        rs += __shfl_xor(rs, 4); rs += __shfl_xor(rs, 8);
        lrow[r] = rs;
    }
#pragma unroll
    for (int r = 0; r < 4; ++r) {
        int row = qs + w * 16 + (l >> 4) * 4 + r;
        float inv = 1.f / lrow[r];
#pragma unroll
        for (int dt = 0; dt < 8; ++dt)
            O[((size_t)(b * S_LEN + row)) * HID + h * DH + dt * 16 + (l & 15)] = f2bf(acc[dt][r] * inv);
    }
}

extern "C" void kernel_launch(void* const* d_in, const int* in_sizes, int n_in,
                              void* d_out, int out_size, void* d_ws, size_t ws_size,
                              hipStream_t stream) {
    (void)in_sizes; (void)n_in; (void)out_size;
    const float* hs  = (const float*)d_in[0];
    const float* WAq = (const float*)d_in[1];
    const float* WBq = (const float*)d_in[2];
    const float* WAk = (const float*)d_in[3];
    const float* WBk = (const float*)d_in[4];
    const float* WAv = (const float*)d_in[5];
    const float* WBv = (const float*)d_in[6];
    const float* Wo  = (const float*)d_in[7];
    const float* fc  = (const float*)d_in[8];
    const float* fs  = (const float*)d_in[9];

    char* ws = (char*)d_ws;
    ushort* Xb    = (ushort*)(ws + 0);            // 4096x2048 bf16
    ushort* WtS   = (ushort*)(ws + 16777216);     // 640x2048 bf16
    ushort* WtBq  = (ushort*)(ws + 19398656);     // 12288x2048 bf16
    ushort* WtWo  = (ushort*)(ws + 69730304);     // 2048x2048 bf16
    float*  Small = (float*) (ws + 78118912);     // 4096x640 f32
    ushort* BqC   = (ushort*)(ws + 88604672);     // chunk: 4096x3072 / full: 4096x12288 bf16

    const bool bigws = (ws_size >= 239599616ull);
    size_t tail = bigws ? 189267968ull : 113770496ull;
    ushort* qB  = (ushort*)(ws + tail);            // (B,H,S,D) bf16 (small-ws path only)
    ushort* kB  = (ushort*)(ws + tail + 16777216); // (B,KV,S,D) bf16
    ushort* vTB = (ushort*)(ws + tail + 25165824); // (B,KV,D,S) bf16
    ushort* OB  = (ushort*)(ws + tail + 33554432); // 4096x2048 bf16

    k_prep<<<9600, 256, 0, stream>>>(hs, WAq, WAk, WAv, WBk, WBv, WBq, Wo,
                                     Xb, WtS, WtBq, WtWo);

    if (bigws) {
        k_mega<<<928, 512, 0, stream>>>(Xb, WtBq, BqC, WtS, Small);
        k_contract_kv<<<4096, 512, 0, stream>>>(Small, fc, fs, kB, vTB);
        k_attn<1><<<1024, 256, 0, stream>>>(BqC, Small, fc, fs, kB, vTB, OB);
    } else {
        k_gemm<float><<<dim3(32, 5), 256, 0, stream>>>(Xb, WtS, Small, 640);
        k_contract_kv<<<4096, 512, 0, stream>>>(Small, fc, fs, kB, vTB);
        for (int c = 0; c < 4; ++c) {
            k_gemm8<<<192, 512, 0, stream>>>(Xb, WtBq + (size_t)c * 3072 * KG, BqC, 3072);
            k_contract_q<<<dim3(4096, 1), 256, 0, stream>>>(BqC, Small, fc, fs, qB, 3072, c * 4);
        }
        k_attn<0><<<1024, 256, 0, stream>>>(qB, Small, fc, fs, kB, vTB, OB);
    }

    k_gemm8h<<<256, 512, 0, stream>>>(OB, WtWo, (float*)d_out, 2048);
}

// Round 19
// 399.984 us; speedup vs baseline: 1.0369x; 1.0369x over previous
//
#include <hip/hip_runtime.h>
#include <hip/hip_bf16.h>

#define S_LEN 2048
#define HID 2048
#define NB 2
#define NH 16
#define NKV 8
#define DH 128
#define RQ 6
#define KG 2048
#define SCALING 0.08838834764831845f

typedef __attribute__((ext_vector_type(8))) short s16x8;
typedef __attribute__((ext_vector_type(4))) float f32x4;

__device__ __forceinline__ float bf2f(ushort u) {
    union { unsigned int i; float f; } v; v.i = ((unsigned int)u) << 16; return v.f;
}
__device__ __forceinline__ ushort f2bf(float f) {
    __hip_bfloat16 h = __float2bfloat16(f);
    return *reinterpret_cast<ushort*>(&h);
}
__device__ __forceinline__ void g2lds16(const void* g, void* l) {
    __builtin_amdgcn_global_load_lds((const __attribute__((address_space(1))) void*)g,
                                     (__attribute__((address_space(3))) void*)l, 16, 0, 0);
}

// ---------------- fused prep: cvt(hs->Xb) + all 7 weight transposes, one launch ----------------
__global__ void k_prep(const float* __restrict__ hs, const float* __restrict__ WAq,
                       const float* __restrict__ WAk, const float* __restrict__ WAv,
                       const float* __restrict__ WBk, const float* __restrict__ WBv,
                       const float* __restrict__ WBq, const float* __restrict__ Wo,
                       ushort* __restrict__ Xb, ushort* __restrict__ WtS,
                       ushort* __restrict__ WtBq, ushort* __restrict__ WtWo) {
    __shared__ ushort tile[64][68];
    int idx = blockIdx.x;
    int t = threadIdx.x;
    if (idx < 2048) {
#pragma unroll
        for (int j = 0; j < 4; ++j) {
            int i = idx * 1024 + t + j * 256;
            float4 v = ((const float4*)hs)[i];
            ushort4 o;
            o.x = f2bf(v.x); o.y = f2bf(v.y); o.z = f2bf(v.z); o.w = f2bf(v.w);
            ((ushort4*)Xb)[i] = o;
        }
        return;
    }
    idx -= 2048;
    const float* in; ushort* out; int Nin, rowOff;
    if (idx < 64)        { in = WAq; out = WtS;  Nin = 96;    rowOff = 0; }
    else if (idx < 96)   { idx -= 64;   in = WAk; out = WtS;  Nin = 16;    rowOff = 96; }
    else if (idx < 128)  { idx -= 96;   in = WAv; out = WtS;  Nin = 16;    rowOff = 112; }
    else if (idx < 256)  { idx -= 128;  in = WBk; out = WtS;  Nin = 256;   rowOff = 128; }
    else if (idx < 384)  { idx -= 256;  in = WBv; out = WtS;  Nin = 256;   rowOff = 384; }
    else if (idx < 6528) { idx -= 384;  in = WBq; out = WtBq; Nin = 12288; rowOff = 0; }
    else                 { idx -= 6528; in = Wo;  out = WtWo; Nin = 2048;  rowOff = 0; }
    int k0 = (idx & 31) * 64, n0 = (idx >> 5) * 64;
#pragma unroll
    for (int i = 0; i < 4; ++i) {
        int f = t + i * 256;
        int r = f >> 4;
        int c = (f & 15) * 4;
        int nn = n0 + c;
        float4 v = make_float4(0.f, 0.f, 0.f, 0.f);
        if (nn < Nin) v = *(const float4*)&in[(size_t)(k0 + r) * Nin + nn];
        ushort4 u;
        u.x = f2bf(v.x); u.y = f2bf(v.y); u.z = f2bf(v.z); u.w = f2bf(v.w);
        *(ushort4*)&tile[r][c] = u;
    }
    __syncthreads();
#pragma unroll
    for (int i = 0; i < 4; ++i) {
        int f = t + i * 256;
        int nr = f >> 4;
        int kc = (f & 15) * 4;
        int nn = n0 + nr;
        if (nn < Nin) {
            ushort4 u;
            u.x = tile[kc][nr]; u.y = tile[kc + 1][nr];
            u.z = tile[kc + 2][nr]; u.w = tile[kc + 3][nr];
            *(ushort4*)&out[(size_t)(rowOff + nn) * KG + k0 + kc] = u;
        }
    }
}

// ---------------- generic bf16 GEMM: A[M][2048] @ Bt[N][2048]^T -> C[M][ldc], 128x128 tile ----------------
__device__ __forceinline__ void stc(float* p, float v) { *p = v; }
__device__ __forceinline__ void stc(ushort* p, float v) { *p = f2bf(v); }

template<typename OutT>
__global__ __launch_bounds__(256, 2) void k_gemm(const ushort* __restrict__ A,
                                                 const ushort* __restrict__ Bt,
                                                 OutT* __restrict__ C, int ldc) {
    __shared__ ushort lA[128 * 64];
    __shared__ ushort lB[128 * 64];
    const int tid = threadIdx.x;
    const int l = tid & 63, w = tid >> 6;
    const int gx = gridDim.x;
    int flat = blockIdx.y * gx + blockIdx.x;
    const int nwg = gx * gridDim.y;
    if ((nwg & 7) == 0) {
        int qq = nwg >> 3;
        flat = (flat & 7) * qq + (flat >> 3);
    }
    const int m0 = (flat % gx) * 128, n0 = (flat / gx) * 128;
    const int wm = w >> 1, wn = w & 1;
    f32x4 acc[4][4] = {};
    const int swz = 16 * ((tid & 7) ^ ((tid >> 3) & 7));
    const int rowbase = tid >> 3;

    for (int k0 = 0; k0 < KG; k0 += 64) {
#pragma unroll
        for (int i = 0; i < 4; ++i) {
            int row = rowbase + i * 32;
            const char* srcA = (const char*)A + (((size_t)(m0 + row) * KG + k0) * 2) + swz;
            g2lds16(srcA, (char*)lA + tid * 16 + i * 4096);
            const char* srcB = (const char*)Bt + (((size_t)(n0 + row) * KG + k0) * 2) + swz;
            g2lds16(srcB, (char*)lB + tid * 16 + i * 4096);
        }
        __syncthreads();
#pragma unroll
        for (int kk = 0; kk < 2; ++kk) {
            s16x8 af[4], bfr[4];
            const int kb = kk * 64 + (l >> 4) * 16;
#pragma unroll
            for (int mf = 0; mf < 4; ++mf) {
                int row = wm * 64 + mf * 16 + (l & 15);
                af[mf] = *(const s16x8*)((const char*)lA + row * 128 + (kb ^ ((row & 7) << 4)));
            }
#pragma unroll
            for (int nf = 0; nf < 4; ++nf) {
                int row = wn * 64 + nf * 16 + (l & 15);
                bfr[nf] = *(const s16x8*)((const char*)lB + row * 128 + (kb ^ ((row & 7) << 4)));
            }
#pragma unroll
            for (int mf = 0; mf < 4; ++mf)
#pragma unroll
                for (int nf = 0; nf < 4; ++nf)
                    acc[mf][nf] = __builtin_amdgcn_mfma_f32_16x16x32_bf16(af[mf], bfr[nf], acc[mf][nf], 0, 0, 0);
        }
        __syncthreads();
    }
#pragma unroll
    for (int mf = 0; mf < 4; ++mf)
#pragma unroll
        for (int r = 0; r < 4; ++r) {
            int row = m0 + wm * 64 + mf * 16 + (l >> 4) * 4 + r;
#pragma unroll
            for (int nf = 0; nf < 4; ++nf) {
                int col = n0 + wn * 64 + nf * 16 + (l & 15);
                stc(C + (size_t)row * ldc + col, acc[mf][nf][r]);
            }
        }
}

// ---------------- mega launch: gemm8(Bq, blocks 0..767) + Small GEMM (blocks 768..927) ----------------
__global__ __launch_bounds__(512, 2) void k_mega(const ushort* __restrict__ Xb,
                                                 const ushort* __restrict__ WtBq,
                                                 ushort* __restrict__ BqC,
                                                 const ushort* __restrict__ WtS,
                                                 float* __restrict__ Small) {
    __shared__ char sB[131072];
    const int tid = threadIdx.x;
    const int l = tid & 63, wid = tid >> 6;

    if (blockIdx.x < 768) {
        const ushort* A = Xb;
        const ushort* Bt = WtBq;
        ushort* C = BqC;
        const int ldc = 12288;
        const int wr = wid >> 2, wc = wid & 3;

        int flat = blockIdx.x;
        {
            int qq = 768 >> 3;
            flat = (flat & 7) * qq + (flat >> 3);
        }
        const int m0 = (flat & 15) * 256;
        const int n0 = (flat >> 4) * 256;

        const int rb = tid >> 3;
        const int swz = 16 * ((tid & 7) ^ (rb & 7));
        const char* pAh[2][2];
        const char* pBh[2][2];
#pragma unroll
        for (int h = 0; h < 2; ++h)
#pragma unroll
            for (int j = 0; j < 2; ++j) {
                pAh[h][j] = (const char*)A + (size_t)(m0 + j * 128 + h * 64 + rb) * (KG * 2) + swz;
                pBh[h][j] = (const char*)Bt + (size_t)(n0 + (j * 2 + (tid >> 8)) * 64 + h * 32 + (rb & 31)) * (KG * 2) + swz;
            }

        f32x4 acc[8][4] = {};
        s16x8 af[4][2], bf[4][2];

        const int arow = (l & 15) * 128;
        const int kxor0 = (0 * 64 + (l >> 4) * 16) ^ ((l & 7) << 4);
        const int kxor1 = (1 * 64 + (l >> 4) * 16) ^ ((l & 7) << 4);

#define STG_A(T, D, H)                                                                     \
    do {                                                                                   \
        g2lds16(pAh[H][0] + (size_t)(T) * 128, sB + (D) * 65536 + (H) * 16384 + tid * 16); \
        g2lds16(pAh[H][1] + (size_t)(T) * 128, sB + (D) * 65536 + (H) * 16384 + 8192 + tid * 16); \
    } while (0)
#define STG_B(T, D, H)                                                                     \
    do {                                                                                   \
        g2lds16(pBh[H][0] + (size_t)(T) * 128, sB + (D) * 65536 + 32768 + (H) * 16384 + tid * 16); \
        g2lds16(pBh[H][1] + (size_t)(T) * 128, sB + (D) * 65536 + 32768 + (H) * 16384 + 8192 + tid * 16); \
    } while (0)
#define RD_A(D, MH)                                                                        \
    do {                                                                                   \
        const char* ab = sB + (D) * 65536 + (MH) * 16384 + wr * 8192;                      \
        _Pragma("unroll") for (int mi = 0; mi < 4; ++mi) {                                 \
            af[mi][0] = *(const s16x8*)(ab + mi * 2048 + arow + kxor0);                    \
            af[mi][1] = *(const s16x8*)(ab + mi * 2048 + arow + kxor1);                    \
        }                                                                                  \
    } while (0)
#define RD_B(D, BH)                                                                        \
    do {                                                                                   \
        const char* bb = sB + (D) * 65536 + 32768 + (BH) * 16384 + wc * 4096;              \
        _Pragma("unroll") for (int ni = 0; ni < 2; ++ni) {                                 \
            bf[(BH) * 2 + ni][0] = *(const s16x8*)(bb + ni * 2048 + arow + kxor0);         \
            bf[(BH) * 2 + ni][1] = *(const s16x8*)(bb + ni * 2048 + arow + kxor1);         \
        }                                                                                  \
    } while (0)
#define QMFMA(MQ, NQ)                                                                      \
    do {                                                                                   \
        __builtin_amdgcn_s_setprio(1);                                                     \
        _Pragma("unroll") for (int mi = 0; mi < 4; ++mi)                                   \
        _Pragma("unroll") for (int ni = 0; ni < 2; ++ni)                                   \
        _Pragma("unroll") for (int k2 = 0; k2 < 2; ++k2)                                   \
            acc[(MQ) * 4 + mi][(NQ) * 2 + ni] = __builtin_amdgcn_mfma_f32_16x16x32_bf16(   \
                af[mi][k2], bf[(NQ) * 2 + ni][k2], acc[(MQ) * 4 + mi][(NQ) * 2 + ni], 0, 0, 0); \
        __builtin_amdgcn_s_setprio(0);                                                     \
    } while (0)
#define BAR()                                   \
    do {                                        \
        asm volatile("" ::: "memory");          \
        __builtin_amdgcn_s_barrier();           \
        asm volatile("" ::: "memory");          \
    } while (0)
#define VM6() asm volatile("s_waitcnt vmcnt(6)" ::: "memory")
#define VM0() asm volatile("s_waitcnt vmcnt(0)" ::: "memory")

        STG_A(0, 0, 0); STG_A(0, 0, 1); STG_B(0, 0, 0); STG_B(0, 0, 1);
        STG_B(1, 1, 0); STG_B(1, 1, 1); STG_A(1, 1, 0);
        VM6();
        BAR();

        for (int i = 0; i < 16; ++i) {
            const bool last = (i == 15);
            const int t1 = 2 * i + 1, t2 = 2 * i + 2, t3 = 2 * i + 3;
            RD_A(0, 0); RD_B(0, 0);
            STG_A(t1, 1, 1);
            BAR(); QMFMA(0, 0); BAR();
            RD_B(0, 1);
            if (!last) STG_A(t2, 0, 0);
            BAR(); QMFMA(0, 1); BAR();
            RD_A(0, 1);
            if (!last) STG_B(t2, 0, 0);
            BAR(); QMFMA(1, 1); BAR();
            if (!last) { STG_B(t2, 0, 1); VM6(); } else { VM0(); }
            BAR(); QMFMA(1, 0); BAR();
            RD_A(1, 0); RD_B(1, 0);
            if (!last) STG_A(t2, 0, 1);
            BAR(); QMFMA(0, 0); BAR();
            RD_B(1, 1);
            if (!last) STG_B(t3, 1, 0);
            BAR(); QMFMA(0, 1); BAR();
            RD_A(1, 1);
            if (!last) STG_B(t3, 1, 1);
            BAR(); QMFMA(1, 1); BAR();
            if (!last) { STG_A(t3, 1, 0); VM6(); }
            BAR(); QMFMA(1, 0); BAR();
        }

#undef STG_A
#undef STG_B
#undef RD_A
#undef RD_B
#undef QMFMA
#undef BAR
#undef VM6
#undef VM0

#pragma unroll
        for (int mf = 0; mf < 8; ++mf)
#pragma unroll
            for (int r = 0; r < 4; ++r) {
                int row = m0 + wr * 128 + mf * 16 + (l >> 4) * 4 + r;
#pragma unroll
                for (int nf = 0; nf < 4; ++nf) {
                    int col = n0 + wc * 64 + nf * 16 + (l & 15);
                    C[(size_t)row * ldc + col] = f2bf(acc[mf][nf][r]);
                }
            }
    } else {
        // ---- Small GEMM: Xb @ WtS^T -> Small[4096][640] f32, 128x128 tile ----
        ushort* lA = (ushort*)sB;
        ushort* lB = (ushort*)(sB + 16384);
        int flat = blockIdx.x - 768;
        {
            int qq = 160 >> 3;
            flat = (flat & 7) * qq + (flat >> 3);
        }
        const int m0 = (flat % 32) * 128, n0 = (flat / 32) * 128;
        const int w = wid;
        const int wm = (w & 3) >> 1, wn = w & 1;
        f32x4 acc[4][4] = {};
        const int swz = 16 * ((tid & 7) ^ ((tid >> 3) & 7));
        const int rowbase = tid >> 3;

        for (int k0 = 0; k0 < KG; k0 += 64) {
#pragma unroll
            for (int i = 0; i < 2; ++i) {
                int row = rowbase + i * 64;
                const char* srcA = (const char*)Xb + (((size_t)(m0 + row) * KG + k0) * 2) + swz;
                g2lds16(srcA, (char*)lA + tid * 16 + i * 8192);
                const char* srcB = (const char*)WtS + (((size_t)(n0 + row) * KG + k0) * 2) + swz;
                g2lds16(srcB, (char*)lB + tid * 16 + i * 8192);
            }
            __syncthreads();
            if (w < 4) {
#pragma unroll
                for (int kk = 0; kk < 2; ++kk) {
                    s16x8 af[4], bfr[4];
                    const int kb = kk * 64 + (l >> 4) * 16;
#pragma unroll
                    for (int mf = 0; mf < 4; ++mf) {
                        int row = wm * 64 + mf * 16 + (l & 15);
                        af[mf] = *(const s16x8*)((const char*)lA + row * 128 + (kb ^ ((row & 7) << 4)));
                    }
#pragma unroll
                    for (int nf = 0; nf < 4; ++nf) {
                        int row = wn * 64 + nf * 16 + (l & 15);
                        bfr[nf] = *(const s16x8*)((const char*)lB + row * 128 + (kb ^ ((row & 7) << 4)));
                    }
#pragma unroll
                    for (int mf = 0; mf < 4; ++mf)
#pragma unroll
                        for (int nf = 0; nf < 4; ++nf)
                            acc[mf][nf] = __builtin_amdgcn_mfma_f32_16x16x32_bf16(af[mf], bfr[nf], acc[mf][nf], 0, 0, 0);
                }
            }
            __syncthreads();
        }
        if (w < 4) {
#pragma unroll
            for (int mf = 0; mf < 4; ++mf)
#pragma unroll
                for (int r = 0; r < 4; ++r) {
                    int row = m0 + wm * 64 + mf * 16 + (l >> 4) * 4 + r;
#pragma unroll
                    for (int nf = 0; nf < 4; ++nf) {
                        int col = n0 + wn * 64 + nf * 16 + (l & 15);
                        Small[(size_t)row * 640 + col] = acc[mf][nf][r];
                    }
                }
        }
    }
}

// ---------------- 256x256 8-phase counted-vmcnt GEMM (small-ws fallback only) ----------------
__global__ __launch_bounds__(512, 2) void k_gemm8(const ushort* __restrict__ A,
                                                  const ushort* __restrict__ Bt,
                                                  ushort* __restrict__ C, int ldc) {
    __shared__ char sB[131072];
    const int tid = threadIdx.x;
    const int l = tid & 63, wid = tid >> 6;
    const int wr = wid >> 2, wc = wid & 3;

    int flat = blockIdx.x;
    const int nwg = gridDim.x;
    if ((nwg & 7) == 0) {
        int qq = nwg >> 3;
        flat = (flat & 7) * qq + (flat >> 3);
    }
    const int m0 = (flat & 15) * 256;
    const int n0 = (flat >> 4) * 256;

    const int rb = tid >> 3;
    const int swz = 16 * ((tid & 7) ^ (rb & 7));
    const char* pAh[2][2];
    const char* pBh[2][2];
#pragma unroll
    for (int h = 0; h < 2; ++h)
#pragma unroll
        for (int j = 0; j < 2; ++j) {
            pAh[h][j] = (const char*)A + (size_t)(m0 + j * 128 + h * 64 + rb) * (KG * 2) + swz;
            pBh[h][j] = (const char*)Bt + (size_t)(n0 + (j * 2 + (tid >> 8)) * 64 + h * 32 + (rb & 31)) * (KG * 2) + swz;
        }

    f32x4 acc[8][4] = {};
    s16x8 af[4][2], bf[4][2];

    const int arow = (l & 15) * 128;
    const int kxor0 = (0 * 64 + (l >> 4) * 16) ^ ((l & 7) << 4);
    const int kxor1 = (1 * 64 + (l >> 4) * 16) ^ ((l & 7) << 4);

#define STG_A(T, D, H)                                                                     \
    do {                                                                                   \
        g2lds16(pAh[H][0] + (size_t)(T) * 128, sB + (D) * 65536 + (H) * 16384 + tid * 16); \
        g2lds16(pAh[H][1] + (size_t)(T) * 128, sB + (D) * 65536 + (H) * 16384 + 8192 + tid * 16); \
    } while (0)
#define STG_B(T, D, H)                                                                     \
    do {                                                                                   \
        g2lds16(pBh[H][0] + (size_t)(T) * 128, sB + (D) * 65536 + 32768 + (H) * 16384 + tid * 16); \
        g2lds16(pBh[H][1] + (size_t)(T) * 128, sB + (D) * 65536 + 32768 + (H) * 16384 + 8192 + tid * 16); \
    } while (0)
#define RD_A(D, MH)                                                                        \
    do {                                                                                   \
        const char* ab = sB + (D) * 65536 + (MH) * 16384 + wr * 8192;                      \
        _Pragma("unroll") for (int mi = 0; mi < 4; ++mi) {                                 \
            af[mi][0] = *(const s16x8*)(ab + mi * 2048 + arow + kxor0);                    \
            af[mi][1] = *(const s16x8*)(ab + mi * 2048 + arow + kxor1);                    \
        }                                                                                  \
    } while (0)
#define RD_B(D, BH)                                                                        \
    do {                                                                                   \
        const char* bb = sB + (D) * 65536 + 32768 + (BH) * 16384 + wc * 4096;              \
        _Pragma("unroll") for (int ni = 0; ni < 2; ++ni) {                                 \
            bf[(BH) * 2 + ni][0] = *(const s16x8*)(bb + ni * 2048 + arow + kxor0);         \
            bf[(BH) * 2 + ni][1] = *(const s16x8*)(bb + ni * 2048 + arow + kxor1);         \
        }                                                                                  \
    } while (0)
#define QMFMA(MQ, NQ)                                                                      \
    do {                                                                                   \
        __builtin_amdgcn_s_setprio(1);                                                     \
        _Pragma("unroll") for (int mi = 0; mi < 4; ++mi)                                   \
        _Pragma("unroll") for (int ni = 0; ni < 2; ++ni)                                   \
        _Pragma("unroll") for (int k2 = 0; k2 < 2; ++k2)                                   \
            acc[(MQ) * 4 + mi][(NQ) * 2 + ni] = __builtin_amdgcn_mfma_f32_16x16x32_bf16(   \
                af[mi][k2], bf[(NQ) * 2 + ni][k2], acc[(MQ) * 4 + mi][(NQ) * 2 + ni], 0, 0, 0); \
        __builtin_amdgcn_s_setprio(0);                                                     \
    } while (0)
#define BAR()                                   \
    do {                                        \
        asm volatile("" ::: "memory");          \
        __builtin_amdgcn_s_barrier();           \
        asm volatile("" ::: "memory");          \
    } while (0)
#define VM6() asm volatile("s_waitcnt vmcnt(6)" ::: "memory")
#define VM0() asm volatile("s_waitcnt vmcnt(0)" ::: "memory")

    STG_A(0, 0, 0); STG_A(0, 0, 1); STG_B(0, 0, 0); STG_B(0, 0, 1);
    STG_B(1, 1, 0); STG_B(1, 1, 1); STG_A(1, 1, 0);
    VM6();
    BAR();

    for (int i = 0; i < 16; ++i) {
        const bool last = (i == 15);
        const int t1 = 2 * i + 1, t2 = 2 * i + 2, t3 = 2 * i + 3;
        RD_A(0, 0); RD_B(0, 0);
        STG_A(t1, 1, 1);
        BAR(); QMFMA(0, 0); BAR();
        RD_B(0, 1);
        if (!last) STG_A(t2, 0, 0);
        BAR(); QMFMA(0, 1); BAR();
        RD_A(0, 1);
        if (!last) STG_B(t2, 0, 0);
        BAR(); QMFMA(1, 1); BAR();
        if (!last) { STG_B(t2, 0, 1); VM6(); } else { VM0(); }
        BAR(); QMFMA(1, 0); BAR();
        RD_A(1, 0); RD_B(1, 0);
        if (!last) STG_A(t2, 0, 1);
        BAR(); QMFMA(0, 0); BAR();
        RD_B(1, 1);
        if (!last) STG_B(t3, 1, 0);
        BAR(); QMFMA(0, 1); BAR();
        RD_A(1, 1);
        if (!last) STG_B(t3, 1, 1);
        BAR(); QMFMA(1, 1); BAR();
        if (!last) { STG_A(t3, 1, 0); VM6(); }
        BAR(); QMFMA(1, 0); BAR();
    }

#undef STG_A
#undef STG_B
#undef RD_A
#undef RD_B
#undef QMFMA

#pragma unroll
    for (int mf = 0; mf < 8; ++mf)
#pragma unroll
        for (int r = 0; r < 4; ++r) {
            int row = m0 + wr * 128 + mf * 16 + (l >> 4) * 4 + r;
#pragma unroll
            for (int nf = 0; nf < 4; ++nf) {
                int col = n0 + wc * 64 + nf * 16 + (l & 15);
                C[(size_t)row * ldc + col] = f2bf(acc[mf][nf][r]);
            }
        }
#undef BAR
#undef VM6
#undef VM0
}

// ---------------- 128x256 8-phase counted-vmcnt GEMM (BK=64, dbuf), f32 out ----------------
__global__ __launch_bounds__(512, 2) void k_gemm8h(const ushort* __restrict__ A,
                                                   const ushort* __restrict__ Bt,
                                                   float* __restrict__ C, int ldc) {
    __shared__ char sB[98304];
    const int tid = threadIdx.x;
    const int l = tid & 63, wid = tid >> 6;
    const int wr = wid >> 2, wc = wid & 3;

    int flat = blockIdx.x;
    const int nwg = gridDim.x;
    if ((nwg & 7) == 0) {
        int qq = nwg >> 3;
        flat = (flat & 7) * qq + (flat >> 3);
    }
    const int m0 = (flat & 31) * 128;
    const int n0 = (flat >> 5) * 256;

    const int rb = tid >> 3;
    const int swz = 16 * ((tid & 7) ^ (rb & 7));
    const char* pA_[2];
    const char* pB_[2][2];
#pragma unroll
    for (int h = 0; h < 2; ++h) {
        pA_[h] = (const char*)A + (size_t)(m0 + (tid >> 8) * 64 + h * 32 + (rb & 31)) * (KG * 2) + swz;
#pragma unroll
        for (int j = 0; j < 2; ++j)
            pB_[h][j] = (const char*)Bt + (size_t)(n0 + (j * 2 + (tid >> 8)) * 64 + h * 32 + (rb & 31)) * (KG * 2) + swz;
    }

    f32x4 acc[4][4] = {};
    s16x8 af[2][2], bf[4][2];

    const int arow = (l & 15) * 128;
    const int kxor0 = ((l >> 4) * 16) ^ ((l & 7) << 4);
    const int kxor1 = (64 + (l >> 4) * 16) ^ ((l & 7) << 4);

#define STG_AH(T, D, H)                                                                    \
    g2lds16(pA_[H] + (size_t)(T) * 128, sB + (D) * 49152 + (H) * 8192 + tid * 16)
#define STG_BH(T, D, H)                                                                    \
    do {                                                                                   \
        g2lds16(pB_[H][0] + (size_t)(T) * 128, sB + (D) * 49152 + 16384 + (H) * 16384 + tid * 16); \
        g2lds16(pB_[H][1] + (size_t)(T) * 128, sB + (D) * 49152 + 16384 + (H) * 16384 + 8192 + tid * 16); \
    } while (0)
#define RD_AH(D, MH)                                                                       \
    do {                                                                                   \
        const char* ab = sB + (D) * 49152 + (MH) * 8192 + wr * 4096;                       \
        _Pragma("unroll") for (int mi = 0; mi < 2; ++mi) {                                 \
            af[mi][0] = *(const s16x8*)(ab + mi * 2048 + arow + kxor0);                    \
            af[mi][1] = *(const s16x8*)(ab + mi * 2048 + arow + kxor1);                    \
        }                                                                                  \
    } while (0)
#define RD_BH(D, BH)                                                                       \
    do {                                                                                   \
        const char* bb = sB + (D) * 49152 + 16384 + (BH) * 16384 + wc * 4096;              \
        _Pragma("unroll") for (int ni = 0; ni < 2; ++ni) {                                 \
            bf[(BH) * 2 + ni][0] = *(const s16x8*)(bb + ni * 2048 + arow + kxor0);         \
            bf[(BH) * 2 + ni][1] = *(const s16x8*)(bb + ni * 2048 + arow + kxor1);         \
        }                                                                                  \
    } while (0)
#define QMFMAH(MQ, NQ)                                                                     \
    do {                                                                                   \
        __builtin_amdgcn_s_setprio(1);                                                     \
        _Pragma("unroll") for (int mi = 0; mi < 2; ++mi)                                   \
        _Pragma("unroll") for (int ni = 0; ni < 2; ++ni)                                   \
        _Pragma("unroll") for (int k2 = 0; k2 < 2; ++k2)                                   \
            acc[(MQ) * 2 + mi][(NQ) * 2 + ni] = __builtin_amdgcn_mfma_f32_16x16x32_bf16(   \
                af[mi][k2], bf[(NQ) * 2 + ni][k2], acc[(MQ) * 2 + mi][(NQ) * 2 + ni], 0, 0, 0); \
        __builtin_amdgcn_s_setprio(0);                                                     \
    } while (0)
#define BAR()                                   \
    do {                                        \
        asm volatile("" ::: "memory");          \
        __builtin_amdgcn_s_barrier();           \
        asm volatile("" ::: "memory");          \
    } while (0)
#define VM5() asm volatile("s_waitcnt vmcnt(5)" ::: "memory")
#define VM0() asm volatile("s_waitcnt vmcnt(0)" ::: "memory")

    STG_AH(0, 0, 0); STG_AH(0, 0, 1); STG_BH(0, 0, 0); STG_BH(0, 0, 1);
    STG_BH(1, 1, 0); STG_BH(1, 1, 1); STG_AH(1, 1, 0);
    VM5();
    BAR();

    for (int i = 0; i < 16; ++i) {
        const bool last = (i == 15);
        const int t1 = 2 * i + 1, t2 = 2 * i + 2, t3 = 2 * i + 3;
        RD_AH(0, 0); RD_BH(0, 0);
        STG_AH(t1, 1, 1);
        BAR(); QMFMAH(0, 0); BAR();
        RD_BH(0, 1);
        if (!last) STG_AH(t2, 0, 0);
        BAR(); QMFMAH(0, 1); BAR();
        RD_AH(0, 1);
        if (!last) STG_BH(t2, 0, 0);
        BAR(); QMFMAH(1, 1); BAR();
        if (!last) { STG_BH(t2, 0, 1); VM5(); } else { VM0(); }
        BAR(); QMFMAH(1, 0); BAR();
        RD_AH(1, 0); RD_BH(1, 0);
        if (!last) STG_AH(t2, 0, 1);
        BAR(); QMFMAH(0, 0); BAR();
        RD_BH(1, 1);
        if (!last) STG_BH(t3, 1, 0);
        BAR(); QMFMAH(0, 1); BAR();
        RD_AH(1, 1);
        if (!last) STG_BH(t3, 1, 1);
        BAR(); QMFMAH(1, 1); BAR();
        if (!last) { STG_AH(t3, 1, 0); VM5(); }
        BAR(); QMFMAH(1, 0); BAR();
    }

#undef STG_AH
#undef STG_BH
#undef RD_AH
#undef RD_BH
#undef QMFMAH
#undef BAR
#undef VM5
#undef VM0

#pragma unroll
    for (int a = 0; a < 4; ++a)
#pragma unroll
        for (int r = 0; r < 4; ++r) {
            int row = m0 + wr * 64 + a * 16 + (l >> 4) * 4 + r;
#pragma unroll
            for (int b2 = 0; b2 < 4; ++b2) {
                int col = n0 + wc * 64 + b2 * 16 + (l & 15);
                C[(size_t)row * ldc + col] = acc[a][b2][r];
            }
        }
}

// ---------------- contract ranks + rope + scale for q (small-ws fallback only) ----------------
__global__ void k_contract_q(const ushort* __restrict__ bq, const float* __restrict__ small,
                             const float* __restrict__ cosT, const float* __restrict__ sinT,
                             ushort* __restrict__ q, int pitch, int hbase) {
    int srow = blockIdx.x;
    int b = srow >> 11, sl = srow & 2047;
    int t = threadIdx.x;
    int l = t & 63;
    int hloc = blockIdx.y * 4 + (t >> 6);
    int h = hbase + hloc;
    const ushort* bqr = bq + (size_t)srow * pitch + hloc * 768;
    const float* af = small + (size_t)srow * 640 + h * RQ;
    float y0 = 0.f, y1 = 0.f;
#pragma unroll
    for (int r = 0; r < RQ; ++r) {
        float a = af[r];
        ushort2 v = *(const ushort2*)&bqr[r * 128 + 2 * l];
        y0 += a * bf2f(v.x);
        y1 += a * bf2f(v.y);
    }
    float z0 = __shfl_xor(y0, 32);
    float z1 = __shfl_xor(y1, 32);
    int d = (l & 31) * 2;
    float2 cs = *(const float2*)&cosT[sl * 64 + d];
    float2 sn = *(const float2*)&sinT[sl * 64 + d];
    size_t o = ((size_t)(b * NH + h) * S_LEN + sl) * DH;
    ushort2 outv;
    if (l < 32) {
        outv.x = f2bf((y0 * cs.x - z0 * sn.x) * SCALING);
        outv.y = f2bf((y1 * cs.y - z1 * sn.y) * SCALING);
        *(ushort2*)&q[o + d] = outv;
    } else {
        outv.x = f2bf((z0 * sn.x + y0 * cs.x) * SCALING);
        outv.y = f2bf((z1 * sn.y + y1 * cs.y) * SCALING);
        *(ushort2*)&q[o + 64 + d] = outv;
    }
}

// ---------------- contract ranks for k (rope) and v (write v^T) ----------------
__global__ void k_contract_kv(const float* __restrict__ small, const float* __restrict__ cosT,
                              const float* __restrict__ sinT, ushort* __restrict__ kk,
                              ushort* __restrict__ vT) {
    int srow = blockIdx.x;
    int b = srow >> 11, sl = srow & 2047;
    int t = threadIdx.x;                 // 512 threads
    int d2 = t & 63, g = t >> 6;         // g 0..7
    const float* row = small + (size_t)srow * 640;
    float k1 = 0.f, k2 = 0.f, v1 = 0.f, v2 = 0.f;
#pragma unroll
    for (int r = 0; r < 2; ++r) {
        float ak = row[96 + g * 2 + r];
        k1 += ak * row[128 + r * 128 + d2];
        k2 += ak * row[128 + r * 128 + 64 + d2];
        float av = row[112 + g * 2 + r];
        v1 += av * row[384 + r * 128 + d2];
        v2 += av * row[384 + r * 128 + 64 + d2];
    }
    float c = cosT[sl * 64 + d2], s = sinT[sl * 64 + d2];
    float kr1 = k1 * c - k2 * s, kr2 = k1 * s + k2 * c;
    size_t ko = ((size_t)(b * NKV + g) * S_LEN + sl) * DH + d2;
    kk[ko] = f2bf(kr1);
    kk[ko + 64] = f2bf(kr2);
    size_t vo = ((size_t)(b * NKV + g) * DH + d2) * S_LEN + sl;
    vT[vo] = f2bf(v1);
    vT[vo + (size_t)64 * S_LEN] = f2bf(v2);
}

// ---------------- softcap probability: exp(50*tanh(x/50) - 50) via Pade(5,4) tanh ----------------
__device__ __forceinline__ float softcap_p(float x) {
    float z = x * 0.02f;
    float z2 = z * z;
    float num = z * fmaf(z2, z2 + 105.f, 945.f);
    float den = fmaf(z2, fmaf(z2, 15.f, 420.f), 945.f);
    return __expf(fmaf(50.f, __fdividef(num, den), -50.f));
}

// ---------------- flash attention: R2 geometry, R15 empirical-best schedule ----------------
// NOTE: the R15 mapping (descending qb, hh in low bit) measured best (401us). Both structured
// balance attempts (R16 consecutive-4, R17 stride-32 round-robin) REGRESSED — block->CU
// assignment is not predictable by simple models on this chip. Treat this mapping as an
// empirical constant; do not re-derive.
template<int FUSEQ>
__global__ __launch_bounds__(256, 2) void k_attn(const ushort* __restrict__ qsrc,
                                                 const float* __restrict__ small,
                                                 const float* __restrict__ cosT,
                                                 const float* __restrict__ sinT,
                                                 const ushort* __restrict__ kk,
                                                 const ushort* __restrict__ vT,
                                                 ushort* __restrict__ O) {
    __shared__ char sK[16384];   // [64 tok][128 d] bf16, swizzled
    __shared__ char sV[16384];   // [128 d][64 tok] bf16, swizzled
    __shared__ char sP[8192];    // per-wave 2KB x 4
    const int f = blockIdx.x;        // 0..1023
    const int xcd = f & 7;
    const int j = f >> 3;            // 0..127
    const int bg = xcd * 2 + (j >> 6);
    const int rem = j & 63;
    const int qb = 31 - (rem >> 1);
    const int hh = rem & 1;
    const int b = bg >> 3, g = bg & 7;
    const int h = g * 2 + hh;
    const int tid = threadIdx.x, l = tid & 63, w = tid >> 6;   // w 0..3
    const int qs = qb * 64;
    const int q0 = qs + w * 16;

    s16x8 qf[4];
    if (FUSEQ) {
        const int row = q0 + (l & 15);
        const int srow = b * S_LEN + row;
        const float* af = small + (size_t)srow * 640 + h * RQ;
        const ushort* bqr = qsrc + (size_t)srow * 12288 + h * 768;
        const int k8 = (l >> 4) * 8;
#pragma unroll
        for (int grp = 0; grp < 2; ++grp) {
            const int dbase = grp * 32 + k8;
            float x1[8] = {}, x2[8] = {};
#pragma unroll
            for (int r = 0; r < RQ; ++r) {
                float a = af[r];
                s16x8 v1 = *(const s16x8*)&bqr[r * 128 + dbase];
                s16x8 v2 = *(const s16x8*)&bqr[r * 128 + 64 + dbase];
#pragma unroll
                for (int e = 0; e < 8; ++e) {
                    x1[e] = fmaf(a, bf2f((ushort)v1[e]), x1[e]);
                    x2[e] = fmaf(a, bf2f((ushort)v2[e]), x2[e]);
                }
            }
            const float* cp = &cosT[row * 64 + dbase];
            const float* sp = &sinT[row * 64 + dbase];
            s16x8 lo, hi;
#pragma unroll
            for (int e = 0; e < 8; ++e) {
                float c = cp[e], sv = sp[e];
                lo[e] = (short)f2bf((x1[e] * c - x2[e] * sv) * SCALING);
                hi[e] = (short)f2bf((x1[e] * sv + x2[e] * c) * SCALING);
            }
            qf[grp] = lo;
            qf[grp + 2] = hi;
        }
    } else {
        const ushort* qbase = qsrc + ((size_t)(b * NH + h) * S_LEN) * DH;
        const char* qrow = (const char*)(qbase + (size_t)(q0 + (l & 15)) * DH);
#pragma unroll
        for (int ds = 0; ds < 4; ++ds)
            qf[ds] = *(const s16x8*)(qrow + ds * 64 + (l >> 4) * 16);
    }

    f32x4 acc[8] = {};
    float lrow[4] = {0.f, 0.f, 0.f, 0.f};

    const size_t kgbase = ((size_t)(b * NKV + g) * S_LEN) * DH * 2;
    const size_t vgbase = ((size_t)(b * NKV + g) * DH) * S_LEN * 2;

    const int jt0 = (qs > 1023) ? ((qs - 1023) >> 6) : 0;
    const int ibase = q0 + (l >> 4) * 4;

    for (int jt = jt0; jt <= qb; ++jt) {
#pragma unroll
        for (int i = 0; i < 4; ++i) {
            int row = (tid >> 4) + i * 16;
            int colb = (tid & 15) * 16;
            const char* src = (const char*)kk + kgbase + ((size_t)(jt * 64 + row)) * 256 + (colb ^ ((row & 7) << 4));
            g2lds16(src, sK + tid * 16 + i * 4096);
        }
#pragma unroll
        for (int i = 0; i < 4; ++i) {
            int row = (tid >> 3) + i * 32;
            int colb = (tid & 7) * 16;
            const char* src = (const char*)vT + vgbase + (size_t)row * 4096 + (size_t)jt * 128 + (colb ^ ((row & 7) << 4));
            g2lds16(src, sV + tid * 16 + i * 4096);
        }
        __syncthreads();

        const bool diag = (jt == qb);
        const bool wclip = (jt == jt0) && (qs > 1023);

        f32x4 sc[4] = {};
#pragma unroll
        for (int ct = 0; ct < 4; ++ct) {
            if (diag && ct > w) continue;
            f32x4 z = {};
            int row = ct * 16 + (l & 15);
#pragma unroll
            for (int ds = 0; ds < 4; ++ds) {
                int kb = ds * 64 + (l >> 4) * 16;
                s16x8 kf = *(const s16x8*)(sK + row * 256 + (kb ^ ((row & 7) << 4)));
                z = __builtin_amdgcn_mfma_f32_16x16x32_bf16(qf[ds], kf, z, 0, 0, 0);
            }
            sc[ct] = z;
        }
        float p[4][4];
        if (!diag && !wclip) {
#pragma unroll
            for (int ct = 0; ct < 4; ++ct)
#pragma unroll
                for (int r = 0; r < 4; ++r) {
                    float pe = softcap_p(sc[ct][r]);
                    p[ct][r] = pe;
                    lrow[r] += pe;
                }
        } else if (diag) {
#pragma unroll
            for (int ct = 0; ct < 4; ++ct) {
                if (ct > w) {
#pragma unroll
                    for (int r = 0; r < 4; ++r) p[ct][r] = 0.f;
                    continue;
                }
                int j2 = jt * 64 + ct * 16 + (l & 15);
#pragma unroll
                for (int r = 0; r < 4; ++r) {
                    float pe = softcap_p(sc[ct][r]);
                    pe = (j2 <= ibase + r) ? pe : 0.f;
                    p[ct][r] = pe;
                    lrow[r] += pe;
                }
            }
        } else {
#pragma unroll
            for (int ct = 0; ct < 4; ++ct) {
                int j2 = jt * 64 + ct * 16 + (l & 15);
#pragma unroll
                for (int r = 0; r < 4; ++r) {
                    float pe = softcap_p(sc[ct][r]);
                    pe = (j2 > ibase + r - 1024) ? pe : 0.f;
                    p[ct][r] = pe;
                    lrow[r] += pe;
                }
            }
        }
#pragma unroll
        for (int ct = 0; ct < 4; ++ct) {
            int col = ct * 16 + (l & 15);
#pragma unroll
            for (int r = 0; r < 4; ++r) {
                int row = (l >> 4) * 4 + r;
                *(ushort*)(sP + w * 2048 + row * 128 + ((col * 2) ^ ((row & 7) << 4))) = f2bf(p[ct][r]);
            }
        }
#pragma unroll
        for (int s2 = 0; s2 < 2; ++s2) {
            int rowp = l & 15;
            int kb = s2 * 64 + (l >> 4) * 16;
            s16x8 pf = *(const s16x8*)(sP + w * 2048 + rowp * 128 + (kb ^ ((rowp & 7) << 4)));
#pragma unroll
            for (int dt = 0; dt < 8; ++dt) {
                int d = dt * 16 + (l & 15);
                s16x8 vf = *(const s16x8*)(sV + d * 128 + (kb ^ ((d & 7) << 4)));
                acc[dt] = __builtin_amdgcn_mfma_f32_16x16x32_bf16(pf, vf, acc[dt], 0, 0, 0);
            }
        }
        __syncthreads();
    }
#pragma unroll
    for (int r = 0; r < 4; ++r) {
        float rs = lrow[r];
        rs += __shfl_xor(rs, 1); rs += __shfl_xor(rs, 2);
        rs += __shfl_xor(rs, 4); rs += __shfl_xor(rs, 8);
        lrow[r] = rs;
    }
#pragma unroll
    for (int r = 0; r < 4; ++r) {
        int row = qs + w * 16 + (l >> 4) * 4 + r;
        float inv = 1.f / lrow[r];
#pragma unroll
        for (int dt = 0; dt < 8; ++dt)
            O[((size_t)(b * S_LEN + row)) * HID + h * DH + dt * 16 + (l & 15)] = f2bf(acc[dt][r] * inv);
    }
}

extern "C" void kernel_launch(void* const* d_in, const int* in_sizes, int n_in,
                              void* d_out, int out_size, void* d_ws, size_t ws_size,
                              hipStream_t stream) {
    (void)in_sizes; (void)n_in; (void)out_size;
    const float* hs  = (const float*)d_in[0];
    const float* WAq = (const float*)d_in[1];
    const float* WBq = (const float*)d_in[2];
    const float* WAk = (const float*)d_in[3];
    const float* WBk = (const float*)d_in[4];
    const float* WAv = (const float*)d_in[5];
    const float* WBv = (const float*)d_in[6];
    const float* Wo  = (const float*)d_in[7];
    const float* fc  = (const float*)d_in[8];
    const float* fs  = (const float*)d_in[9];

    char* ws = (char*)d_ws;
    ushort* Xb    = (ushort*)(ws + 0);            // 4096x2048 bf16
    ushort* WtS   = (ushort*)(ws + 16777216);     // 640x2048 bf16
    ushort* WtBq  = (ushort*)(ws + 19398656);     // 12288x2048 bf16
    ushort* WtWo  = (ushort*)(ws + 69730304);     // 2048x2048 bf16
    float*  Small = (float*) (ws + 78118912);     // 4096x640 f32
    ushort* BqC   = (ushort*)(ws + 88604672);     // chunk: 4096x3072 / full: 4096x12288 bf16

    const bool bigws = (ws_size >= 239599616ull);
    size_t tail = bigws ? 189267968ull : 113770496ull;
    ushort* qB  = (ushort*)(ws + tail);            // (B,H,S,D) bf16 (small-ws path only)
    ushort* kB  = (ushort*)(ws + tail + 16777216); // (B,KV,S,D) bf16
    ushort* vTB = (ushort*)(ws + tail + 25165824); // (B,KV,D,S) bf16
    ushort* OB  = (ushort*)(ws + tail + 33554432); // 4096x2048 bf16

    k_prep<<<9600, 256, 0, stream>>>(hs, WAq, WAk, WAv, WBk, WBv, WBq, Wo,
                                     Xb, WtS, WtBq, WtWo);

    if (bigws) {
        k_mega<<<928, 512, 0, stream>>>(Xb, WtBq, BqC, WtS, Small);
        k_contract_kv<<<4096, 512, 0, stream>>>(Small, fc, fs, kB, vTB);
        k_attn<1><<<1024, 256, 0, stream>>>(BqC, Small, fc, fs, kB, vTB, OB);
    } else {
        k_gemm<float><<<dim3(32, 5), 256, 0, stream>>>(Xb, WtS, Small, 640);
        k_contract_kv<<<4096, 512, 0, stream>>>(Small, fc, fs, kB, vTB);
        for (int c = 0; c < 4; ++c) {
            k_gemm8<<<192, 512, 0, stream>>>(Xb, WtBq + (size_t)c * 3072 * KG, BqC, 3072);
            k_contract_q<<<dim3(4096, 1), 256, 0, stream>>>(BqC, Small, fc, fs, qB, 3072, c * 4);
        }
        k_attn<0><<<1024, 256, 0, stream>>>(qB, Small, fc, fs, kB, vTB, OB);
    }

    k_gemm8h<<<256, 512, 0, stream>>>(OB, WtWo, (float*)d_out, 2048);
}